// Round 2
// baseline (980.936 us; speedup 1.0000x reference)
//
#include <hip/hip_runtime.h>
#include <hip/hip_bf16.h>

#define NB 512
#define CCH 32
#define LF 1024
#define CL (CCH * LF)  // 32768
#define BN_EPS 1e-5f

typedef __bf16 bf16x8 __attribute__((ext_vector_type(8)));
typedef float f32x4 __attribute__((ext_vector_type(4)));

// Async 16B global->LDS DMA. LDS dest is wave-uniform base + lane*16
// (m104/m108): LDS layout MUST be lane-order contiguous, no padding.
__device__ __forceinline__ void gload16(const __bf16* g, __bf16* l) {
  __builtin_amdgcn_global_load_lds(
      (const __attribute__((address_space(1))) unsigned int*)g,
      (__attribute__((address_space(3))) unsigned int*)l, 16, 0, 0);
}

// fp32 -> bf16 flat convert, 8 elements/thread, exact-size grid.
__global__ __launch_bounds__(256) void cvt_bf16(const float* __restrict__ s,
                                                __bf16* __restrict__ d) {
  const size_t i = ((size_t)blockIdx.x * 256 + threadIdx.x) * 8;
  f32x4 a = *(const f32x4*)(s + i);
  f32x4 b = *(const f32x4*)(s + i + 4);
  bf16x8 o = {(__bf16)a.x, (__bf16)a.y, (__bf16)a.z, (__bf16)a.w,
              (__bf16)b.x, (__bf16)b.y, (__bf16)b.z, (__bf16)b.w};
  *(bf16x8*)(d + i) = o;
}

// m97-style GEMM: C = A @ W^T per channel, A bf16 (N,C,L) slab, W bf16
// (C,3,L,L). 128x128 tile, BK=32, 4 waves x (4x4) 16x16x32 MFMA subtiles.
// LDS layout: [q-octet 0..3][row 0..127][8 bf16] — exactly the DMA lane
// order (s = q*128+row) and the conflict-free frag-read layout.
template <bool RELU, bool BF16OUT>
__global__ __launch_bounds__(256, 3) void gemm_dma(
    const __bf16* __restrict__ Abf, const __bf16* __restrict__ Wall,
    const float* __restrict__ ball, void* __restrict__ outv, int layer) {
  __shared__ __bf16 As[4096];  // 4*128*8 = 8 KB
  __shared__ __bf16 Bs[4096];

  const int tid = threadIdx.x;
  const int c = blockIdx.y;
  const int mtile = blockIdx.x & 3;   // batch tiles (512/128)
  const int ntile = blockIdx.x >> 2;  // feature tiles (1024/128)
  const int m0 = mtile * 128, n0 = ntile * 128;

  const __bf16* A = Abf + (size_t)c * LF;
  const __bf16* Wp = Wall + (size_t)(c * 3 + layer) * LF * LF;
  const float* bias = ball + (size_t)(c * 3 + layer) * LF;

  const int lane = tid & 63;
  const int wv = tid >> 6;
  const int wm = (wv & 1) * 64;
  const int wn = (wv >> 1) * 64;
  const int l15 = lane & 15;
  const int quad = lane >> 4;

  // DMA staging: each wave issues 2 calls per operand per k-iter; call j
  // covers LDS slots s = wv*128 + j*64 + lane; q = s>>7, r = s&127.
  const __bf16 *pa[2], *pb[2];
  __bf16 *la[2], *lb[2];
#pragma unroll
  for (int j = 0; j < 2; ++j) {
    const int s = wv * 128 + j * 64 + lane;
    const int q = s >> 7, r = s & 127;
    pa[j] = A + (size_t)(m0 + r) * CL + q * 8;
    pb[j] = Wp + (size_t)(n0 + r) * LF + q * 8;
    la[j] = As + (wv * 128 + j * 64) * 8;
    lb[j] = Bs + (wv * 128 + j * 64) * 8;
  }

  f32x4 acc[4][4] = {};

  for (int kt = 0; kt < LF / 32; ++kt) {
#pragma unroll
    for (int j = 0; j < 2; ++j) {
      gload16(pa[j], la[j]);
      gload16(pb[j], lb[j]);
      pa[j] += 32;
      pb[j] += 32;
    }
    __syncthreads();  // compiler drains vmcnt before barrier -> DMA visible

    bf16x8 af[4], bfr[4];
#pragma unroll
    for (int mi = 0; mi < 4; ++mi)
      af[mi] = *(const bf16x8*)&As[(quad * 128 + wm + mi * 16 + l15) * 8];
#pragma unroll
    for (int ni = 0; ni < 4; ++ni)
      bfr[ni] = *(const bf16x8*)&Bs[(quad * 128 + wn + ni * 16 + l15) * 8];
#pragma unroll
    for (int mi = 0; mi < 4; ++mi)
#pragma unroll
      for (int ni = 0; ni < 4; ++ni)
        acc[mi][ni] = __builtin_amdgcn_mfma_f32_16x16x32_bf16(
            af[mi], bfr[ni], acc[mi][ni], 0, 0, 0);
    __syncthreads();  // protect LDS from next iter's DMA
  }

  // epilogue: row(batch) = quad*4 + reg, col(feature) = lane&15  (m89)
#pragma unroll
  for (int ni = 0; ni < 4; ++ni) {
    const int feat = n0 + wn + ni * 16 + l15;
    const float bv = bias[feat];
#pragma unroll
    for (int mi = 0; mi < 4; ++mi) {
      const int row0 = m0 + wm + mi * 16 + quad * 4;
#pragma unroll
      for (int r = 0; r < 4; ++r) {
        float v = acc[mi][ni][r] + bv;
        if (RELU) v = fmaxf(v, 0.f);
        if (BF16OUT)
          ((__bf16*)outv)[(size_t)c * LF + (size_t)(row0 + r) * CL + feat] =
              (__bf16)v;
        else
          ((float*)outv)[(size_t)c * LF + (size_t)(row0 + r) * CL + feat] = v;
      }
    }
  }
}

// Fused BN: stats over batch dim + in-place normalize (second pass is
// L1/L2-hot: each block touches only 64 KB). h_norm = h*scale + shift,
// scale = rstd*gamma, shift = beta - mean*scale; biased variance.
__global__ __launch_bounds__(256, 4) void bn_fused(__bf16* __restrict__ H,
                                                   const float* __restrict__ gam,
                                                   const float* __restrict__ bet,
                                                   int bnl) {
  __shared__ float ssum[256], ssq[256], sscale[64], sshift[64];
  const int tid = threadIdx.x;
  const int f = tid & 63, g = tid >> 6;
  const int c = blockIdx.y;
  const int l = blockIdx.x * 64 + f;
  __bf16* col = H + (size_t)c * LF + l;

  float sum = 0.f, sq = 0.f;
  for (int n = g; n < NB; n += 4) {
    float v = (float)col[(size_t)n * CL];
    sum += v;
    sq += v * v;
  }
  ssum[tid] = sum;
  ssq[tid] = sq;
  __syncthreads();
  if (tid < 64) {
    sum = ssum[f] + ssum[64 + f] + ssum[128 + f] + ssum[192 + f];
    sq = ssq[f] + ssq[64 + f] + ssq[128 + f] + ssq[192 + f];
    const float mean = sum * (1.f / NB);
    const float var = sq * (1.f / NB) - mean * mean;
    const float rstd = rsqrtf(var + BN_EPS);
    const float sc = rstd * gam[(size_t)(c * 2 + bnl) * LF + l];
    sscale[f] = sc;
    sshift[f] = bet[(size_t)(c * 2 + bnl) * LF + l] - mean * sc;
  }
  __syncthreads();
  const float sc = sscale[f], sh = sshift[f];
  for (int n = g; n < NB; n += 4) {
    float v = (float)col[(size_t)n * CL];
    col[(size_t)n * CL] = (__bf16)(v * sc + sh);
  }
}

extern "C" void kernel_launch(void* const* d_in, const int* in_sizes, int n_in,
                              void* d_out, int out_size, void* d_ws,
                              size_t ws_size, hipStream_t stream) {
  const float* x = (const float*)d_in[0];
  const float* W = (const float*)d_in[1];
  const float* b = (const float*)d_in[2];
  const float* gamma = (const float*)d_in[3];
  const float* beta = (const float*)d_in[4];
  float* out = (float*)d_out;

  // ws: Wbf 201 MB | xbf 32 MB | h1 32 MB | h2 32 MB  (~300 MB < ws_size)
  __bf16* Wbf = (__bf16*)d_ws;
  __bf16* xbf = Wbf + (size_t)CCH * 3 * LF * LF;
  __bf16* h1 = xbf + (size_t)NB * CL;
  __bf16* h2 = h1 + (size_t)NB * CL;

  const dim3 blk(256);
  const dim3 ggrid(32, CCH);  // 4 m-tiles * 8 n-tiles, 32 channels
  const dim3 bgrid(16, CCH);  // 1024 feats / 64, 32 channels

  // 1) convert W (100.66M) and x (16.78M) fp32->bf16
  cvt_bf16<<<dim3((CCH * 3 * LF * LF) / (8 * 256)), blk, 0, stream>>>(W, Wbf);
  cvt_bf16<<<dim3(((size_t)NB * CL) / (8 * 256)), blk, 0, stream>>>(x, xbf);

  // 2) layer 0: h1 = relu(x @ W0^T + b0), bf16
  gemm_dma<true, true><<<ggrid, blk, 0, stream>>>(xbf, Wbf, b, h1, 0);
  bn_fused<<<bgrid, blk, 0, stream>>>(h1, gamma, beta, 0);
  // 3) layer 1: h2 = relu(BN(h1) @ W1^T + b1), bf16
  gemm_dma<true, true><<<ggrid, blk, 0, stream>>>(h1, Wbf, b, h2, 1);
  bn_fused<<<bgrid, blk, 0, stream>>>(h2, gamma, beta, 1);
  // 4) layer 2: out = BN(h2) @ W2^T + b2, fp32
  gemm_dma<false, false><<<ggrid, blk, 0, stream>>>(h2, Wbf, b, out, 2);
}

// Round 3
// 957.727 us; speedup vs baseline: 1.0242x; 1.0242x over previous
//
#include <hip/hip_runtime.h>
#include <hip/hip_bf16.h>

#define NB 512
#define CCH 32
#define LF 1024
#define CL (CCH * LF)
#define BN_EPS 1e-5f

typedef __bf16 bf16x8 __attribute__((ext_vector_type(8)));
typedef __bf16 bf16x4 __attribute__((ext_vector_type(4)));
typedef float f32x4 __attribute__((ext_vector_type(4)));

// Async 16B global->LDS DMA; LDS dest is wave-uniform base + lane*16.
__device__ __forceinline__ void gload16(const __bf16* g, __bf16* l) {
  __builtin_amdgcn_global_load_lds(
      (const __attribute__((address_space(1))) unsigned int*)g,
      (__attribute__((address_space(3))) unsigned int*)l, 16, 0, 0);
}

// --- W pre-swizzle: fp32 W -> bf16 DMA-linear tile images -----------------
// Wswz[(c*3+layer)*8 + ntile] is a 32-kt sequence of 8KB images; image slot
// s=q*128+r, elem j  <=  W[c,layer][n0+r][kt*32+q*8+j]. GEMM B-staging then
// reads each image with 4 fully-contiguous 1KB DMA instructions.
__global__ __launch_bounds__(256) void cvt_w(const float* __restrict__ W,
                                             __bf16* __restrict__ Wswz) {
  __shared__ __bf16 img[4096];
  const int tid = threadIdx.x;
  const int bid = blockIdx.x;   // (c*3+layer)*8 + ntile, 768 blocks
  const int n0 = (bid & 7) * 128;
  const float* Wr = W + (size_t)(bid >> 3) * LF * LF;
  __bf16* dst = Wswz + (size_t)bid * 131072;
  const int sr = tid >> 3, kseg = tid & 7;
  const int q = kseg >> 1, bsub = (kseg & 1) * 4;
  for (int kt = 0; kt < 32; ++kt) {
    const int k0 = kt * 32 + kseg * 4;
#pragma unroll
    for (int i = 0; i < 4; ++i) {
      const int r = i * 32 + sr;
      f32x4 v = *(const f32x4*)(Wr + (size_t)(n0 + r) * LF + k0);
      bf16x4 o = {(__bf16)v.x, (__bf16)v.y, (__bf16)v.z, (__bf16)v.w};
      *(bf16x4*)&img[(q * 128 + r) * 8 + bsub] = o;
    }
    __syncthreads();
    *(bf16x8*)(dst + kt * 4096 + tid * 16) = *(bf16x8*)&img[tid * 16];
    *(bf16x8*)(dst + kt * 4096 + tid * 16 + 8) = *(bf16x8*)&img[tid * 16 + 8];
    __syncthreads();
  }
}

// --- x: (n,c,l) fp32 -> (c,n,l) bf16 channel-major ------------------------
__global__ __launch_bounds__(256) void cvt_x(const float* __restrict__ x,
                                             __bf16* __restrict__ hA) {
  const int n = blockIdx.x, c = blockIdx.y;
  const float* src = x + ((size_t)n * CCH + c) * LF + threadIdx.x * 4;
  __bf16* dst = hA + ((size_t)c * NB + n) * LF + threadIdx.x * 4;
  f32x4 v = *(const f32x4*)src;
  bf16x4 o = {(__bf16)v.x, (__bf16)v.y, (__bf16)v.z, (__bf16)v.w};
  *(bf16x4*)dst = o;
}

// --- GEMM: C = A @ W^T per channel --------------------------------------
// A: bf16 channel-major (c,n,l), row stride LF (2KB). B: Wswz linear images.
// 128x128 tile, BK=32, 4 waves x 4x4 16x16x32 MFMA. LDS [q][row][8] bf16.
template <bool RELU, bool BF16OUT>
__global__ __launch_bounds__(256, 3) void gemm_dma(
    const __bf16* __restrict__ Abf, const __bf16* __restrict__ Wswz,
    const float* __restrict__ ball, void* __restrict__ outv, int layer) {
  __shared__ __bf16 As[4096];
  __shared__ __bf16 Bs[4096];

  const int tid = threadIdx.x;
  const int c = blockIdx.y;
  const int mtile = blockIdx.x >> 3;  // stride-8 x shares ntile -> same XCD
  const int ntile = blockIdx.x & 7;
  const int m0 = mtile * 128, n0 = ntile * 128;

  const __bf16* A = Abf + (size_t)c * NB * LF;
  const float* bias = ball + (size_t)(c * 3 + layer) * LF;

  const int lane = tid & 63;
  const int wv = tid >> 6;
  const int wm = (wv & 1) * 64;
  const int wn = (wv >> 1) * 64;
  const int l15 = lane & 15;
  const int quad = lane >> 4;

  const __bf16 *pa[2], *pb[2];
  __bf16 *la[2], *lb[2];
#pragma unroll
  for (int j = 0; j < 2; ++j) {
    const int s = wv * 128 + j * 64 + lane;
    const int q = s >> 7, r = s & 127;
    pa[j] = A + (size_t)(m0 + r) * LF + q * 8;          // rows 2KB apart
    pb[j] = Wswz + (size_t)((c * 3 + layer) * 8 + ntile) * 131072 + s * 8;
    la[j] = As + (wv * 128 + j * 64) * 8;
    lb[j] = Bs + (wv * 128 + j * 64) * 8;
  }

  f32x4 acc[4][4] = {};

  for (int kt = 0; kt < 32; ++kt) {
#pragma unroll
    for (int j = 0; j < 2; ++j) {
      gload16(pa[j], la[j]);   // 64 rows x 16B, 2KB stride
      gload16(pb[j], lb[j]);   // 1KB fully contiguous
      pa[j] += 32;
      pb[j] += 4096;
    }
    __syncthreads();

    bf16x8 af[4], bfr[4];
#pragma unroll
    for (int mi = 0; mi < 4; ++mi)
      af[mi] = *(const bf16x8*)&As[(quad * 128 + wm + mi * 16 + l15) * 8];
#pragma unroll
    for (int ni = 0; ni < 4; ++ni)
      bfr[ni] = *(const bf16x8*)&Bs[(quad * 128 + wn + ni * 16 + l15) * 8];
#pragma unroll
    for (int mi = 0; mi < 4; ++mi)
#pragma unroll
      for (int ni = 0; ni < 4; ++ni)
        acc[mi][ni] = __builtin_amdgcn_mfma_f32_16x16x32_bf16(
            af[mi], bfr[ni], acc[mi][ni], 0, 0, 0);
    __syncthreads();
  }

  // epilogue: row(batch)=quad*4+reg, col(feature)=lane&15
#pragma unroll
  for (int ni = 0; ni < 4; ++ni) {
    const int feat = n0 + wn + ni * 16 + l15;
    const float bv = bias[feat];
#pragma unroll
    for (int mi = 0; mi < 4; ++mi) {
      const int row0 = m0 + wm + mi * 16 + quad * 4;
#pragma unroll
      for (int r = 0; r < 4; ++r) {
        float v = acc[mi][ni][r] + bv;
        if (RELU) v = fmaxf(v, 0.f);
        if (BF16OUT)  // channel-major bf16, lanes write 32B contiguous
          ((__bf16*)outv)[((size_t)c * NB + row0 + r) * LF + feat] = (__bf16)v;
        else          // fp32 (n,c,l) for d_out, lanes write 64B contiguous
          ((float*)outv)[((size_t)(row0 + r) * CCH + c) * LF + feat] = v;
      }
    }
  }
}

// --- fused BN over channel-major h (in place) ----------------------------
__global__ __launch_bounds__(256, 4) void bn_fused(__bf16* __restrict__ H,
                                                   const float* __restrict__ gam,
                                                   const float* __restrict__ bet,
                                                   int bnl) {
  __shared__ float ssum[256], ssq[256], sscale[64], sshift[64];
  const int tid = threadIdx.x;
  const int f = tid & 63, g = tid >> 6;
  const int c = blockIdx.y;
  const int l = blockIdx.x * 64 + f;
  __bf16* col = H + (size_t)c * NB * LF + l;  // n-stride LF (2KB)

  float sum = 0.f, sq = 0.f;
  for (int n = g; n < NB; n += 4) {
    float v = (float)col[(size_t)n * LF];
    sum += v;
    sq += v * v;
  }
  ssum[tid] = sum;
  ssq[tid] = sq;
  __syncthreads();
  if (tid < 64) {
    sum = ssum[f] + ssum[64 + f] + ssum[128 + f] + ssum[192 + f];
    sq = ssq[f] + ssq[64 + f] + ssq[128 + f] + ssq[192 + f];
    const float mean = sum * (1.f / NB);
    const float var = sq * (1.f / NB) - mean * mean;
    const float rstd = rsqrtf(var + BN_EPS);
    const float sc = rstd * gam[(size_t)(c * 2 + bnl) * LF + l];
    sscale[f] = sc;
    sshift[f] = bet[(size_t)(c * 2 + bnl) * LF + l] - mean * sc;
  }
  __syncthreads();
  const float sc = sscale[f], sh = sshift[f];
  for (int n = g; n < NB; n += 4) {
    float v = (float)col[(size_t)n * LF];
    col[(size_t)n * LF] = (__bf16)(v * sc + sh);
  }
}

extern "C" void kernel_launch(void* const* d_in, const int* in_sizes, int n_in,
                              void* d_out, int out_size, void* d_ws,
                              size_t ws_size, hipStream_t stream) {
  const float* x = (const float*)d_in[0];
  const float* W = (const float*)d_in[1];
  const float* b = (const float*)d_in[2];
  const float* gamma = (const float*)d_in[3];
  const float* beta = (const float*)d_in[4];
  float* out = (float*)d_out;

  // ws: Wswz 201MB | xbf 32MB | h1 32MB | h2 32MB
  __bf16* Wswz = (__bf16*)d_ws;
  __bf16* xbf = Wswz + (size_t)CCH * 3 * LF * LF;
  __bf16* h1 = xbf + (size_t)NB * CL;
  __bf16* h2 = h1 + (size_t)NB * CL;

  const dim3 blk(256);
  const dim3 ggrid(32, CCH);
  const dim3 bgrid(16, CCH);

  cvt_w<<<dim3(CCH * 3 * 8), blk, 0, stream>>>(W, Wswz);
  cvt_x<<<dim3(NB, CCH), blk, 0, stream>>>(x, xbf);

  gemm_dma<true, true><<<ggrid, blk, 0, stream>>>(xbf, Wswz, b, h1, 0);
  bn_fused<<<bgrid, blk, 0, stream>>>(h1, gamma, beta, 0);
  gemm_dma<true, true><<<ggrid, blk, 0, stream>>>(h1, Wswz, b, h2, 1);
  bn_fused<<<bgrid, blk, 0, stream>>>(h2, gamma, beta, 1);
  gemm_dma<false, false><<<ggrid, blk, 0, stream>>>(h2, Wswz, b, out, 2);
}